// Round 3
// baseline (39887.283 us; speedup 1.0000x reference)
//
#include <hip/hip_runtime.h>
#include <hip/hip_bf16.h>

#define TT 128
#define BB 256
#define OBSD 1024
#define FEATD 512
#define NA 15
#define DD 528
#define GG 2112   // 4*DD
#define KK 1056   // 2*DD
#define SCL 4096.f
#define INV_SCL (1.f/4096.f)

using half8 = __attribute__((ext_vector_type(8))) _Float16;
using f32x4 = __attribute__((ext_vector_type(4))) float;

__device__ __forceinline__ void split1(float v, _Float16& h, _Float16& l){
  h = (_Float16)v;
  l = (_Float16)((v - (float)h) * SCL);
}
__device__ __forceinline__ float sigf(float x){ return 1.f/(1.f + expf(-x)); }

// ---------------- prep kernels ----------------

__global__ void k_prep_w(const float* __restrict__ wih, const float* __restrict__ whh,
                         const float* __restrict__ bih, const float* __restrict__ bhh,
                         _Float16* __restrict__ Wh, _Float16* __restrict__ Wl,
                         float* __restrict__ bias){
  const int n = GG*KK;
  for (int i = blockIdx.x*blockDim.x + threadIdx.x; i < n; i += gridDim.x*blockDim.x){
    int r = i / KK, c = i % KK;
    float v = (c < DD) ? wih[r*DD + c] : whh[r*DD + (c - DD)];
    split1(v, Wh[i], Wl[i]);
    if (i < GG) bias[i] = bih[i] + bhh[i];
  }
}

__global__ void k_conv_encw(const float* __restrict__ src,
                            _Float16* __restrict__ dh, _Float16* __restrict__ dl){
  const int n = FEATD*OBSD;
  for (int i = blockIdx.x*blockDim.x + threadIdx.x; i < n; i += gridDim.x*blockDim.x)
    split1(src[i], dh[i], dl[i]);
}

// x cols 512..527: clipped reward + one_hot(last_action), split planes
__global__ void k_fill_extra(const float* __restrict__ reward, const int* __restrict__ act,
                             _Float16* __restrict__ xh, _Float16* __restrict__ xl){
  int row = blockIdx.x*blockDim.x + threadIdx.x;
  if (row >= TT*BB) return;
  float r = fminf(1.f, fmaxf(-1.f, reward[row]));
  size_t base = (size_t)row*DD + FEATD;
  _Float16 hh, hl;
  split1(r, hh, hl);
  xh[base] = hh; xl[base] = hl;
  int a = act[row];
  #pragma unroll
  for (int i = 0; i < NA; ++i){
    xh[base+1+i] = (i == a) ? (_Float16)1.0f : (_Float16)0.0f;
    xl[base+1+i] = (_Float16)0.0f;
  }
}

// ---------------- encoder GEMM -> x planes cols 0..511 ----------------
__launch_bounds__(256)
__global__ void k_encoder(const float* __restrict__ obs, const _Float16* __restrict__ ench,
                          const _Float16* __restrict__ encl,
                          const float* __restrict__ encb,
                          _Float16* __restrict__ xh, _Float16* __restrict__ xl){
  __shared__ _Float16 Ah[128][40], Al[128][40], Bh[128][40], Bl[128][40];
  const int mt = blockIdx.x, nt = blockIdx.y;
  const int tid = threadIdx.x, w = tid >> 6, l = tid & 63;
  const int wm = (w >> 1)*64, wn = (w & 1)*64;
  const int m0 = mt*128, n0 = nt*128;
  f32x4 acc1[4][4], acc2[4][4];
  #pragma unroll
  for (int m = 0; m < 4; ++m)
    #pragma unroll
    for (int n = 0; n < 4; ++n)
      #pragma unroll
      for (int q = 0; q < 4; ++q){ acc1[m][n][q]=0.f; acc2[m][n][q]=0.f; }

  for (int k0 = 0; k0 < OBSD; k0 += 32){
    {
      int row = tid >> 1, c0 = (tid & 1)*16;
      const float* src = obs + (size_t)(m0+row)*OBSD + k0 + c0;
      #pragma unroll
      for (int cc = 0; cc < 16; ++cc){
        float v = src[cc];
        split1(v, Ah[row][c0+cc], Al[row][c0+cc]);
      }
      const _Float16* bh = ench + (size_t)(n0+row)*OBSD + k0 + c0;
      const _Float16* bl = encl + (size_t)(n0+row)*OBSD + k0 + c0;
      *(half8*)&Bh[row][c0]   = *(const half8*)(bh);
      *(half8*)&Bh[row][c0+8] = *(const half8*)(bh+8);
      *(half8*)&Bl[row][c0]   = *(const half8*)(bl);
      *(half8*)&Bl[row][c0+8] = *(const half8*)(bl+8);
    }
    __syncthreads();
    half8 ah[4], al[4], bh[4], bl[4];
    #pragma unroll
    for (int m = 0; m < 4; ++m){
      ah[m] = *(const half8*)&Ah[wm + m*16 + (l & 15)][(l >> 4)*8];
      al[m] = *(const half8*)&Al[wm + m*16 + (l & 15)][(l >> 4)*8];
    }
    #pragma unroll
    for (int n = 0; n < 4; ++n){
      bh[n] = *(const half8*)&Bh[wn + n*16 + (l & 15)][(l >> 4)*8];
      bl[n] = *(const half8*)&Bl[wn + n*16 + (l & 15)][(l >> 4)*8];
    }
    #pragma unroll
    for (int m = 0; m < 4; ++m)
      #pragma unroll
      for (int n = 0; n < 4; ++n){
        acc1[m][n] = __builtin_amdgcn_mfma_f32_16x16x32_f16(ah[m], bh[n], acc1[m][n], 0, 0, 0);
        acc2[m][n] = __builtin_amdgcn_mfma_f32_16x16x32_f16(ah[m], bl[n], acc2[m][n], 0, 0, 0);
        acc2[m][n] = __builtin_amdgcn_mfma_f32_16x16x32_f16(al[m], bh[n], acc2[m][n], 0, 0, 0);
      }
    __syncthreads();
  }
  #pragma unroll
  for (int m = 0; m < 4; ++m)
    #pragma unroll
    for (int n = 0; n < 4; ++n)
      #pragma unroll
      for (int q = 0; q < 4; ++q){
        int row = m0 + wm + m*16 + (l >> 4)*4 + q;
        int col = n0 + wn + n*16 + (l & 15);
        float v = acc1[m][n][q] + acc2[m][n][q]*INV_SCL + encb[col];
        v = fmaxf(v, 0.f);
        _Float16 hh, hl;
        split1(v, hh, hl);
        size_t off = (size_t)row*DD + col;
        xh[off] = hh; xl[off] = hl;
      }
}

// ---------------- persistent recurrence kernel ----------------
// 132 blocks: mt = bid&3 (64-row batch tile), js = bid>>2 (16-wide hidden strip).
// Per t: phase L0 (x[t], h1(t-1) -> h1(t)), phase L1 (h1(t), h2(t-1)=x[t-1] -> x[t]:=h2(t)).
// Flags: flags[t*8 + layer*4 + mt], each counts to 33.
__launch_bounds__(256)
__global__ void k_recur(_Float16* xh, _Float16* xl,
                        _Float16* h1h0, _Float16* h1l0,
                        _Float16* h1h1, _Float16* h1l1,
                        float* __restrict__ c1, float* __restrict__ c2,
                        const _Float16* __restrict__ Wh0, const _Float16* __restrict__ Wl0,
                        const _Float16* __restrict__ Wh1, const _Float16* __restrict__ Wl1,
                        const float* __restrict__ bias0, const float* __restrict__ bias1,
                        const int* __restrict__ term, int* flags){
  __shared__ _Float16 Ah[2][64][40], Al[2][64][40], Bh[2][64][40], Bl[2][64][40];
  __shared__ float gbuf[4][64][16];

  const int tid = threadIdx.x, w = tid >> 6, l = tid & 63;
  const int bid = blockIdx.x, mt = bid & 3, js = bid >> 2;
  const int m0 = mt*64, j0 = js*16;
  const int arow = tid >> 2, ac0 = (tid & 3)*8;
  const int garow = (arow >> 4)*DD + j0 + (arow & 15);   // W row for B staging
  const int mr0 = (w & 1)*32, gp = (w >> 1)*2;           // wave tile: 2 Mtiles x 2 gate-tiles

  auto flag_wait = [&](int idx){
    if (tid == 0){
      while (__hip_atomic_load(&flags[idx], __ATOMIC_ACQUIRE, __HIP_MEMORY_SCOPE_AGENT) < 33)
        __builtin_amdgcn_s_sleep(2);
    }
    __syncthreads();
  };
  auto flag_post = [&](int idx){
    __syncthreads();
    if (tid == 0)
      __hip_atomic_fetch_add(&flags[idx], 1, __ATOMIC_RELEASE, __HIP_MEMORY_SCOPE_AGENT);
  };

  auto phase = [&](const _Float16* p1h, const _Float16* p1l,
                   const _Float16* p2h, const _Float16* p2l, bool p2ok,
                   const int* termrow,
                   const _Float16* Wh, const _Float16* Wl, const float* bias,
                   float* cst, _Float16* dh, _Float16* dl){
    const bool ndA = p2ok && (termrow[m0 + arow] == 0);
    half8 sAh[2], sAl[2], sBh[2], sBl[2];

    auto loadG = [&](int it, int sl){
      int col = it*32 + ac0;
      if (col < DD){
        size_t off = (size_t)(m0 + arow)*DD + col;
        sAh[sl] = *(const half8*)(p1h + off);
        sAl[sl] = *(const half8*)(p1l + off);
      } else if (ndA){
        size_t off = (size_t)(m0 + arow)*DD + (col - DD);
        sAh[sl] = *(const half8*)(p2h + off);
        sAl[sl] = *(const half8*)(p2l + off);
      } else {
        half8 z;
        #pragma unroll
        for (int zz = 0; zz < 8; ++zz) z[zz] = (_Float16)0.0f;
        sAh[sl] = z; sAl[sl] = z;
      }
      size_t woff = (size_t)garow*KK + col;
      sBh[sl] = *(const half8*)(Wh + woff);
      sBl[sl] = *(const half8*)(Wl + woff);
    };
    auto stageW = [&](int sl, int s){
      *(half8*)&Ah[s][arow][ac0] = sAh[sl];
      *(half8*)&Al[s][arow][ac0] = sAl[sl];
      *(half8*)&Bh[s][arow][ac0] = sBh[sl];
      *(half8*)&Bl[s][arow][ac0] = sBl[sl];
    };

    f32x4 accm[2][2], accc[2][2];
    #pragma unroll
    for (int mi = 0; mi < 2; ++mi)
      #pragma unroll
      for (int ni = 0; ni < 2; ++ni)
        #pragma unroll
        for (int q = 0; q < 4; ++q){ accm[mi][ni][q]=0.f; accc[mi][ni][q]=0.f; }

    loadG(0, 0); loadG(1, 1);
    stageW(0, 0);
    __syncthreads();
    #pragma unroll 1
    for (int it = 0; it < 33; ++it){
      int s = it & 1;
      if (it + 2 < 33) loadG(it + 2, s);   // reuse freed slot s
      half8 fah[2], fal[2], fbh[2], fbl[2];
      #pragma unroll
      for (int mi = 0; mi < 2; ++mi){
        fah[mi] = *(const half8*)&Ah[s][mr0 + mi*16 + (l & 15)][(l >> 4)*8];
        fal[mi] = *(const half8*)&Al[s][mr0 + mi*16 + (l & 15)][(l >> 4)*8];
      }
      #pragma unroll
      for (int ni = 0; ni < 2; ++ni){
        fbh[ni] = *(const half8*)&Bh[s][(gp + ni)*16 + (l & 15)][(l >> 4)*8];
        fbl[ni] = *(const half8*)&Bl[s][(gp + ni)*16 + (l & 15)][(l >> 4)*8];
      }
      #pragma unroll
      for (int mi = 0; mi < 2; ++mi)
        #pragma unroll
        for (int ni = 0; ni < 2; ++ni){
          accm[mi][ni] = __builtin_amdgcn_mfma_f32_16x16x32_f16(fah[mi], fbh[ni], accm[mi][ni], 0, 0, 0);
          accc[mi][ni] = __builtin_amdgcn_mfma_f32_16x16x32_f16(fah[mi], fbl[ni], accc[mi][ni], 0, 0, 0);
          accc[mi][ni] = __builtin_amdgcn_mfma_f32_16x16x32_f16(fal[mi], fbh[ni], accc[mi][ni], 0, 0, 0);
        }
      if (it + 1 < 33) stageW(s ^ 1, s ^ 1);
      __syncthreads();
    }

    // gate exchange
    #pragma unroll
    for (int mi = 0; mi < 2; ++mi)
      #pragma unroll
      for (int ni = 0; ni < 2; ++ni)
        #pragma unroll
        for (int q = 0; q < 4; ++q)
          gbuf[gp + ni][mr0 + mi*16 + (l >> 4)*4 + q][l & 15] =
            accm[mi][ni][q] + accc[mi][ni][q]*INV_SCL;
    __syncthreads();

    // pointwise LSTM update
    #pragma unroll
    for (int p = 0; p < 4; ++p){
      int f = tid + 256*p;
      int row = f >> 4, col = f & 15;
      int gr = m0 + row, jc = j0 + col;
      float iv = gbuf[0][row][col] + bias[jc];
      float fv = gbuf[1][row][col] + bias[DD + jc];
      float gv = gbuf[2][row][col] + bias[2*DD + jc];
      float ov = gbuf[3][row][col] + bias[3*DD + jc];
      float nd = (termrow[gr] == 0) ? 1.f : 0.f;
      size_t ci = (size_t)gr*DD + jc;
      float cp = cst[ci]*nd;
      float cn = sigf(fv)*cp + sigf(iv)*tanhf(gv);
      float hn = sigf(ov)*tanhf(cn);
      cst[ci] = cn;
      _Float16 hh, hl;
      split1(hn, hh, hl);
      dh[ci] = hh; dl[ci] = hl;
    }
  };

  _Float16* h1h[2] = {h1h0, h1h1};
  _Float16* h1l[2] = {h1l0, h1l1};

  #pragma unroll 1
  for (int t = 0; t < TT; ++t){
    const int* term_t = term + t*BB;
    // ----- layer 0 -----
    if (t >= 1) flag_wait((t-1)*8 + mt);          // h1(t-1) ready
    if (t >= 2) flag_wait((t-2)*8 + 4 + mt);      // WAR: L1(t-2) done reading h1(t-2)
    phase(xh + (size_t)t*BB*DD, xl + (size_t)t*BB*DD,
          h1h[(t+1)&1], h1l[(t+1)&1], t > 0, term_t,
          Wh0, Wl0, bias0, c1, h1h[t&1], h1l[t&1]);
    flag_post(t*8 + mt);
    // ----- layer 1 -----
    flag_wait(t*8 + mt);                           // h1(t) fully ready (all strips)
    if (t >= 1) flag_wait((t-1)*8 + 4 + mt);       // h2(t-1)=x[t-1] ready
    phase(h1h[t&1], h1l[t&1],
          xh + (size_t)(t-1)*BB*DD, xl + (size_t)(t-1)*BB*DD, t > 0, term_t,
          Wh1, Wl1, bias1, c2,
          xh + (size_t)t*BB*DD, xl + (size_t)t*BB*DD);
    flag_post(t*8 + 4 + mt);
  }
}

// ---------------- heads: logits/baseline/action ----------------
__launch_bounds__(256)
__global__ void k_heads(const _Float16* __restrict__ oh, const _Float16* __restrict__ ol,
                        const float* __restrict__ polw, const float* __restrict__ basew,
                        const float* __restrict__ polb, const float* __restrict__ baseb,
                        float* __restrict__ dout){
  __shared__ _Float16 Ah[128][40], Al[128][40];
  __shared__ _Float16 Bh[16][552], Bl[16][552];
  const int bid = blockIdx.x;
  const int tid = threadIdx.x, w = tid >> 6, l = tid & 63;
  const int m0 = bid*128;

  for (int i = tid; i < 16*544; i += 256){
    int r = i / 544, c = i % 544;
    float v = 0.f;
    if (c < DD) v = (r < NA) ? polw[r*DD + c] : basew[c];
    split1(v, Bh[r][c], Bl[r][c]);
  }
  __syncthreads();

  f32x4 acc1[2], acc2[2];
  #pragma unroll
  for (int m = 0; m < 2; ++m)
    #pragma unroll
    for (int q = 0; q < 4; ++q){ acc1[m][q]=0.f; acc2[m][q]=0.f; }

  for (int it = 0; it < 17; ++it){
    const int k0 = it*32;
    {
      int row = tid >> 1, c0 = (tid & 1)*16;
      size_t off = (size_t)(m0+row)*DD + k0 + c0;   // overreads pad; B=0 there
      *(half8*)&Ah[row][c0]   = *(const half8*)(oh + off);
      *(half8*)&Ah[row][c0+8] = *(const half8*)(oh + off + 8);
      *(half8*)&Al[row][c0]   = *(const half8*)(ol + off);
      *(half8*)&Al[row][c0+8] = *(const half8*)(ol + off + 8);
    }
    __syncthreads();
    half8 fbh = *(const half8*)&Bh[l & 15][k0 + (l >> 4)*8];
    half8 fbl = *(const half8*)&Bl[l & 15][k0 + (l >> 4)*8];
    #pragma unroll
    for (int m = 0; m < 2; ++m){
      half8 fah = *(const half8*)&Ah[w*32 + m*16 + (l & 15)][(l >> 4)*8];
      half8 fal = *(const half8*)&Al[w*32 + m*16 + (l & 15)][(l >> 4)*8];
      acc1[m] = __builtin_amdgcn_mfma_f32_16x16x32_f16(fah, fbh, acc1[m], 0, 0, 0);
      acc2[m] = __builtin_amdgcn_mfma_f32_16x16x32_f16(fah, fbl, acc2[m], 0, 0, 0);
      acc2[m] = __builtin_amdgcn_mfma_f32_16x16x32_f16(fal, fbh, acc2[m], 0, 0, 0);
    }
    __syncthreads();
  }

  const int a = l & 15;
  const size_t base_off = (size_t)TT*BB*NA;
  const size_t act_off  = base_off + (size_t)TT*BB;
  #pragma unroll
  for (int m = 0; m < 2; ++m)
    #pragma unroll
    for (int q = 0; q < 4; ++q){
      int r = m0 + w*32 + m*16 + (l >> 4)*4 + q;
      float v = acc1[m][q] + acc2[m][q]*INV_SCL + ((a < NA) ? polb[a] : baseb[0]);
      float key = (a < NA) ? v : -3.4e38f;
      int ki = a;
      #pragma unroll
      for (int s = 1; s < 16; s <<= 1){
        float ov = __shfl_xor(key, s, 64);
        int   oi = __shfl_xor(ki,  s, 64);
        if (ov > key || (ov == key && oi < ki)){ key = ov; ki = oi; }
      }
      if (a < NA) dout[(size_t)r*NA + a] = v;
      if (a == NA) dout[base_off + r] = v;
      if (a == 0)  dout[act_off + r] = (float)ki;
    }
}

// ---------------- launch ----------------
extern "C" void kernel_launch(void* const* d_in, const int* in_sizes, int n_in,
                              void* d_out, int out_size, void* d_ws, size_t ws_size,
                              hipStream_t stream){
  const float* obs        = (const float*)d_in[0];
  const int*   last_act   = (const int*)  d_in[1];
  const float* reward     = (const float*)d_in[2];
  const int*   terminated = (const int*)  d_in[3];
  const float* enc_w      = (const float*)d_in[4];
  const float* enc_b      = (const float*)d_in[5];
  const float* w_ih0      = (const float*)d_in[6];
  const float* w_hh0      = (const float*)d_in[7];
  const float* b_ih0      = (const float*)d_in[8];
  const float* b_hh0      = (const float*)d_in[9];
  const float* w_ih1      = (const float*)d_in[10];
  const float* w_hh1      = (const float*)d_in[11];
  const float* b_ih1      = (const float*)d_in[12];
  const float* b_hh1      = (const float*)d_in[13];
  const float* pol_w      = (const float*)d_in[14];
  const float* pol_b      = (const float*)d_in[15];
  const float* base_w     = (const float*)d_in[16];
  const float* base_b     = (const float*)d_in[17];

  char* ws = (char*)d_ws;
  size_t o = 0;
  auto alloc = [&](size_t bytes){ size_t r = o; o += (bytes + 255) & ~(size_t)255; return r; };

  _Float16* Wh0   = (_Float16*)(ws + alloc((size_t)GG*KK*2));
  _Float16* Wl0   = (_Float16*)(ws + alloc((size_t)GG*KK*2));
  _Float16* Wh1   = (_Float16*)(ws + alloc((size_t)GG*KK*2));
  _Float16* Wl1   = (_Float16*)(ws + alloc((size_t)GG*KK*2));
  float* bias0    = (float*)(ws + alloc((size_t)GG*4));
  float* bias1    = (float*)(ws + alloc((size_t)GG*4));
  _Float16* ench  = (_Float16*)(ws + alloc((size_t)FEATD*OBSD*2));
  _Float16* encl  = (_Float16*)(ws + alloc((size_t)FEATD*OBSD*2));
  _Float16* xh    = (_Float16*)(ws + alloc((size_t)TT*BB*DD*2 + 4096));  // x / h2-out hi plane
  _Float16* xl    = (_Float16*)(ws + alloc((size_t)TT*BB*DD*2 + 4096));  // lo plane
  char*  states   = ws + o;
  _Float16* h1h0  = (_Float16*)(ws + alloc((size_t)BB*DD*2));
  _Float16* h1l0  = (_Float16*)(ws + alloc((size_t)BB*DD*2));
  _Float16* h1h1  = (_Float16*)(ws + alloc((size_t)BB*DD*2));
  _Float16* h1l1  = (_Float16*)(ws + alloc((size_t)BB*DD*2));
  float* c1       = (float*)(ws + alloc((size_t)BB*DD*4));
  float* c2       = (float*)(ws + alloc((size_t)BB*DD*4));
  int*   flags    = (int*)(ws + alloc((size_t)TT*8*4));
  size_t state_bytes = (size_t)(ws + o - states);

  hipMemsetAsync(states, 0, state_bytes, stream);

  k_prep_w<<<2048, 256, 0, stream>>>(w_ih0, w_hh0, b_ih0, b_hh0, Wh0, Wl0, bias0);
  k_prep_w<<<2048, 256, 0, stream>>>(w_ih1, w_hh1, b_ih1, b_hh1, Wh1, Wl1, bias1);
  k_conv_encw<<<2048, 256, 0, stream>>>(enc_w, ench, encl);
  k_fill_extra<<<TT*BB/256, 256, 0, stream>>>(reward, last_act, xh, xl);

  dim3 eg(TT*BB/128, FEATD/128);
  k_encoder<<<eg, 256, 0, stream>>>(obs, ench, encl, enc_b, xh, xl);

  k_recur<<<132, 256, 0, stream>>>(xh, xl, h1h0, h1l0, h1h1, h1l1, c1, c2,
                                   Wh0, Wl0, Wh1, Wl1, bias0, bias1,
                                   terminated, flags);

  k_heads<<<TT*BB/128, 256, 0, stream>>>(xh, xl, pol_w, base_w, pol_b, base_b, (float*)d_out);
}

// Round 4
// 5911.679 us; speedup vs baseline: 6.7472x; 6.7472x over previous
//
#include <hip/hip_runtime.h>
#include <hip/hip_bf16.h>

#define TT 128
#define BB 256
#define OBSD 1024
#define FEATD 512
#define NA 15
#define DD 528
#define GG 2112   // 4*DD
#define KK 1056   // 2*DD
#define SCL 4096.f
#define INV_SCL (1.f/4096.f)

using half8 = __attribute__((ext_vector_type(8))) _Float16;
using f32x4 = __attribute__((ext_vector_type(4))) float;

__device__ __forceinline__ void split1(float v, _Float16& h, _Float16& l){
  h = (_Float16)v;
  l = (_Float16)((v - (float)h) * SCL);
}
__device__ __forceinline__ float sigf(float x){ return 1.f/(1.f + expf(-x)); }

// 16B read executed at the L3 coherence point (bypasses possibly-stale L2)
__device__ __forceinline__ half8 bypass16(const _Float16* p){
  union { half8 v; unsigned long long u[2]; } t;
  t.u[0] = __hip_atomic_load((const unsigned long long*)p,     __ATOMIC_RELAXED, __HIP_MEMORY_SCOPE_SYSTEM);
  t.u[1] = __hip_atomic_load((const unsigned long long*)(p+4), __ATOMIC_RELAXED, __HIP_MEMORY_SCOPE_SYSTEM);
  return t.v;
}
__device__ __forceinline__ void bypass_store_h(_Float16* p, _Float16 v){
  __hip_atomic_store((unsigned short*)p, __builtin_bit_cast(unsigned short, v),
                     __ATOMIC_RELAXED, __HIP_MEMORY_SCOPE_SYSTEM);
}

// ---------------- prep kernels ----------------

__global__ void k_prep_w(const float* __restrict__ wih, const float* __restrict__ whh,
                         const float* __restrict__ bih, const float* __restrict__ bhh,
                         _Float16* __restrict__ Wh, _Float16* __restrict__ Wl,
                         float* __restrict__ bias){
  const int n = GG*KK;
  for (int i = blockIdx.x*blockDim.x + threadIdx.x; i < n; i += gridDim.x*blockDim.x){
    int r = i / KK, c = i % KK;
    float v = (c < DD) ? wih[r*DD + c] : whh[r*DD + (c - DD)];
    split1(v, Wh[i], Wl[i]);
    if (i < GG) bias[i] = bih[i] + bhh[i];
  }
}

__global__ void k_conv_encw(const float* __restrict__ src,
                            _Float16* __restrict__ dh, _Float16* __restrict__ dl){
  const int n = FEATD*OBSD;
  for (int i = blockIdx.x*blockDim.x + threadIdx.x; i < n; i += gridDim.x*blockDim.x)
    split1(src[i], dh[i], dl[i]);
}

__global__ void k_fill_extra(const float* __restrict__ reward, const int* __restrict__ act,
                             _Float16* __restrict__ xh, _Float16* __restrict__ xl){
  int row = blockIdx.x*blockDim.x + threadIdx.x;
  if (row >= TT*BB) return;
  float r = fminf(1.f, fmaxf(-1.f, reward[row]));
  size_t base = (size_t)row*DD + FEATD;
  _Float16 hh, hl;
  split1(r, hh, hl);
  xh[base] = hh; xl[base] = hl;
  int a = act[row];
  #pragma unroll
  for (int i = 0; i < NA; ++i){
    xh[base+1+i] = (i == a) ? (_Float16)1.0f : (_Float16)0.0f;
    xl[base+1+i] = (_Float16)0.0f;
  }
}

// ---------------- encoder GEMM -> x planes cols 0..511 ----------------
__launch_bounds__(256)
__global__ void k_encoder(const float* __restrict__ obs, const _Float16* __restrict__ ench,
                          const _Float16* __restrict__ encl,
                          const float* __restrict__ encb,
                          _Float16* __restrict__ xh, _Float16* __restrict__ xl){
  __shared__ _Float16 Ah[128][40], Al[128][40], Bh[128][40], Bl[128][40];
  const int mt = blockIdx.x, nt = blockIdx.y;
  const int tid = threadIdx.x, w = tid >> 6, l = tid & 63;
  const int wm = (w >> 1)*64, wn = (w & 1)*64;
  const int m0 = mt*128, n0 = nt*128;
  f32x4 acc1[4][4], acc2[4][4];
  #pragma unroll
  for (int m = 0; m < 4; ++m)
    #pragma unroll
    for (int n = 0; n < 4; ++n)
      #pragma unroll
      for (int q = 0; q < 4; ++q){ acc1[m][n][q]=0.f; acc2[m][n][q]=0.f; }

  for (int k0 = 0; k0 < OBSD; k0 += 32){
    {
      int row = tid >> 1, c0 = (tid & 1)*16;
      const float* src = obs + (size_t)(m0+row)*OBSD + k0 + c0;
      #pragma unroll
      for (int cc = 0; cc < 16; ++cc){
        float v = src[cc];
        split1(v, Ah[row][c0+cc], Al[row][c0+cc]);
      }
      const _Float16* bh = ench + (size_t)(n0+row)*OBSD + k0 + c0;
      const _Float16* bl = encl + (size_t)(n0+row)*OBSD + k0 + c0;
      *(half8*)&Bh[row][c0]   = *(const half8*)(bh);
      *(half8*)&Bh[row][c0+8] = *(const half8*)(bh+8);
      *(half8*)&Bl[row][c0]   = *(const half8*)(bl);
      *(half8*)&Bl[row][c0+8] = *(const half8*)(bl+8);
    }
    __syncthreads();
    half8 ah[4], al[4], bh[4], bl[4];
    #pragma unroll
    for (int m = 0; m < 4; ++m){
      ah[m] = *(const half8*)&Ah[wm + m*16 + (l & 15)][(l >> 4)*8];
      al[m] = *(const half8*)&Al[wm + m*16 + (l & 15)][(l >> 4)*8];
    }
    #pragma unroll
    for (int n = 0; n < 4; ++n){
      bh[n] = *(const half8*)&Bh[wn + n*16 + (l & 15)][(l >> 4)*8];
      bl[n] = *(const half8*)&Bl[wn + n*16 + (l & 15)][(l >> 4)*8];
    }
    #pragma unroll
    for (int m = 0; m < 4; ++m)
      #pragma unroll
      for (int n = 0; n < 4; ++n){
        acc1[m][n] = __builtin_amdgcn_mfma_f32_16x16x32_f16(ah[m], bh[n], acc1[m][n], 0, 0, 0);
        acc2[m][n] = __builtin_amdgcn_mfma_f32_16x16x32_f16(ah[m], bl[n], acc2[m][n], 0, 0, 0);
        acc2[m][n] = __builtin_amdgcn_mfma_f32_16x16x32_f16(al[m], bh[n], acc2[m][n], 0, 0, 0);
      }
    __syncthreads();
  }
  #pragma unroll
  for (int m = 0; m < 4; ++m)
    #pragma unroll
    for (int n = 0; n < 4; ++n)
      #pragma unroll
      for (int q = 0; q < 4; ++q){
        int row = m0 + wm + m*16 + (l >> 4)*4 + q;
        int col = n0 + wn + n*16 + (l & 15);
        float v = acc1[m][n][q] + acc2[m][n][q]*INV_SCL + encb[col];
        v = fmaxf(v, 0.f);
        _Float16 hh, hl;
        split1(v, hh, hl);
        size_t off = (size_t)row*DD + col;
        xh[off] = hh; xl[off] = hl;
      }
}

// ---------------- persistent recurrence kernel (fence-free relaxed protocol) ----------------
// 132 blocks: mt = bid&3 (64-row batch tile), js = bid>>2 (16-wide hidden strip).
// Wave w owns M rows w*16..w*16+15 and ALL 4 gates (no cross-wave gate exchange).
// Shared h state (h1 planes, h2 -> x alias) accessed ONLY via relaxed system-scope
// atomics (sc0 sc1: executed at L3) -> no L2 invalidation, W stays L2-resident.
__launch_bounds__(256)
__global__ void k_recur(_Float16* xh, _Float16* xl,
                        _Float16* h1h0, _Float16* h1l0,
                        _Float16* h1h1, _Float16* h1l1,
                        const _Float16* __restrict__ Wh0, const _Float16* __restrict__ Wl0,
                        const _Float16* __restrict__ Wh1, const _Float16* __restrict__ Wl1,
                        const float* __restrict__ bias0, const float* __restrict__ bias1,
                        const int* __restrict__ term, int* flags){
  __shared__ _Float16 Ah[2][64][36], Al[2][64][36], Bh[2][64][36], Bl[2][64][36];

  const int tid = threadIdx.x, w = tid >> 6, l = tid & 63;
  const int bid = blockIdx.x, mt = bid & 3, js = bid >> 2;
  const int m0 = mt*64, j0 = js*16;
  const int arow = tid >> 2, ac0 = (tid & 3)*8;
  const int garow = (arow >> 4)*DD + j0 + (arow & 15);
  const int prow0 = m0 + w*16 + ((l >> 4) << 2);
  const int jcol = j0 + (l & 15);

  float c1r[4] = {0.f,0.f,0.f,0.f};
  float c2r[4] = {0.f,0.f,0.f,0.f};

  half8 r0a, r0al, r0b, r0bl;   // prefetch reg set 0
  half8 r1a, r1al, r1b, r1bl;   // prefetch reg set 1

  f32x4 accm[4], accc[4];

  auto zacc = [&](){
    #pragma unroll
    for (int g = 0; g < 4; ++g)
      #pragma unroll
      for (int q = 0; q < 4; ++q){ accm[g][q] = 0.f; accc[g][q] = 0.f; }
  };

  auto flag_wait = [&](int idx){
    if (tid == 0){
      while (__hip_atomic_load(&flags[idx], __ATOMIC_RELAXED, __HIP_MEMORY_SCOPE_SYSTEM) < 33)
        __builtin_amdgcn_s_sleep(2);
    }
    __syncthreads();
  };
  auto flag_post = [&](int idx){
    asm volatile("s_waitcnt vmcnt(0)" ::: "memory");   // own h stores drained to L3
    __syncthreads();                                   // all threads' stores drained
    if (tid == 0)
      __hip_atomic_fetch_add(&flags[idx], 1, __ATOMIC_RELAXED, __HIP_MEMORY_SCOPE_SYSTEM);
  };

  // one phase = gates GEMM over k-range + (optionally) epilogue; built from pieces:
  auto loadG = [&](int it, bool p1byp, const _Float16* p1h, const _Float16* p1l,
                   const _Float16* p2h, const _Float16* p2l, bool ndA,
                   const _Float16* Wh, const _Float16* Wl,
                   half8& Ra, half8& Ral, half8& Rb, half8& Rbl){
    int col = it*32 + ac0;
    if (col < DD){
      size_t off = (size_t)(m0 + arow)*DD + col;
      if (p1byp){ Ra = bypass16(p1h + off); Ral = bypass16(p1l + off); }
      else      { Ra = *(const half8*)(p1h + off); Ral = *(const half8*)(p1l + off); }
    } else {
      if (ndA){
        size_t off = (size_t)(m0 + arow)*DD + (col - DD);
        Ra = bypass16(p2h + off); Ral = bypass16(p2l + off);
      } else {
        half8 z;
        #pragma unroll
        for (int zz = 0; zz < 8; ++zz) z[zz] = (_Float16)0.0f;
        Ra = z; Ral = z;
      }
    }
    size_t woff = (size_t)garow*KK + col;
    Rb  = *(const half8*)(Wh + woff);
    Rbl = *(const half8*)(Wl + woff);
  };

  auto stage0 = [&](){ *(half8*)&Ah[0][arow][ac0] = r0a; *(half8*)&Al[0][arow][ac0] = r0al;
                       *(half8*)&Bh[0][arow][ac0] = r0b; *(half8*)&Bl[0][arow][ac0] = r0bl; };
  auto stage1 = [&](){ *(half8*)&Ah[1][arow][ac0] = r1a; *(half8*)&Al[1][arow][ac0] = r1al;
                       *(half8*)&Bh[1][arow][ac0] = r1b; *(half8*)&Bl[1][arow][ac0] = r1bl; };

  auto domfma = [&](int s){
    half8 fah = *(const half8*)&Ah[s][w*16 + (l & 15)][(l >> 4)*8];
    half8 fal = *(const half8*)&Al[s][w*16 + (l & 15)][(l >> 4)*8];
    #pragma unroll
    for (int g = 0; g < 4; ++g){
      half8 fbh = *(const half8*)&Bh[s][g*16 + (l & 15)][(l >> 4)*8];
      half8 fbl = *(const half8*)&Bl[s][g*16 + (l & 15)][(l >> 4)*8];
      accm[g] = __builtin_amdgcn_mfma_f32_16x16x32_f16(fah, fbh, accm[g], 0, 0, 0);
      accc[g] = __builtin_amdgcn_mfma_f32_16x16x32_f16(fah, fbl, accc[g], 0, 0, 0);
      accc[g] = __builtin_amdgcn_mfma_f32_16x16x32_f16(fal, fbh, accc[g], 0, 0, 0);
    }
  };

  auto runrange = [&](int it0, int it1, bool p1byp,
                      const _Float16* p1h, const _Float16* p1l,
                      const _Float16* p2h, const _Float16* p2l, bool ndA,
                      const _Float16* Wh, const _Float16* Wl){
    const int R = it1 - it0;
    loadG(it0, p1byp, p1h, p1l, p2h, p2l, ndA, Wh, Wl, r0a, r0al, r0b, r0bl);
    stage0();
    if (R > 1) loadG(it0+1, p1byp, p1h, p1l, p2h, p2l, ndA, Wh, Wl, r1a, r1al, r1b, r1bl);
    __syncthreads();
    #pragma unroll 1
    for (int i = 0; i < R; i += 2){
      // step A (LDS slot 0, reg set 0 free after staged)
      if (i + 2 < R) loadG(it0+i+2, p1byp, p1h, p1l, p2h, p2l, ndA, Wh, Wl, r0a, r0al, r0b, r0bl);
      domfma(0);
      if (i + 1 < R) stage1();
      __syncthreads();
      if (i + 1 >= R) break;
      // step B (LDS slot 1, reg set 1 free after staged)
      if (i + 3 < R) loadG(it0+i+3, p1byp, p1h, p1l, p2h, p2l, ndA, Wh, Wl, r1a, r1al, r1b, r1bl);
      domfma(1);
      if (i + 2 < R) stage0();
      __syncthreads();
    }
  };

  auto epilogue = [&](const float* bias, float* cr, _Float16* dh, _Float16* dl,
                      const int* term_t){
    #pragma unroll
    for (int q = 0; q < 4; ++q){
      int row = prow0 + q;
      float iv = accm[0][q] + accc[0][q]*INV_SCL + bias[jcol];
      float fv = accm[1][q] + accc[1][q]*INV_SCL + bias[DD + jcol];
      float gv = accm[2][q] + accc[2][q]*INV_SCL + bias[2*DD + jcol];
      float ov = accm[3][q] + accc[3][q]*INV_SCL + bias[3*DD + jcol];
      float cp = (term_t[row] == 0) ? cr[q] : 0.f;
      float cn = sigf(fv)*cp + sigf(iv)*tanhf(gv);
      float hn = sigf(ov)*tanhf(cn);
      cr[q] = cn;
      _Float16 hh, hl;
      split1(hn, hh, hl);
      size_t off = (size_t)row*DD + jcol;
      bypass_store_h(dh + off, hh);
      bypass_store_h(dl + off, hl);
    }
  };

  _Float16* h1h[2] = {h1h0, h1h1};
  _Float16* h1l[2] = {h1l0, h1l1};

  #pragma unroll 1
  for (int t = 0; t < TT; ++t){
    const int* term_t = term + t*BB;
    const bool ndrow = (term_t[m0 + arow] == 0);
    const bool p2ok = (t > 0);
    const bool ndA = p2ok && ndrow;
    _Float16* xth = xh + (size_t)t*BB*DD;
    _Float16* xtl = xl + (size_t)t*BB*DD;
    _Float16* xph = xh + (size_t)(t > 0 ? t-1 : 0)*BB*DD;
    _Float16* xpl = xl + (size_t)(t > 0 ? t-1 : 0)*BB*DD;

    // ===== layer 0: gates = [x(t) | h1(t-1)*nd] @ W0^T =====
    zacc();
    // x-half first (no dependency): slabs [0,16) are pure x
    runrange(0, 16, false, xth, xtl, h1h[(t+1)&1], h1l[(t+1)&1], ndA, Wh0, Wl0);
    if (t >= 1) flag_wait((t-1)*8 + mt);              // h1(t-1) ready (all strips)
    runrange(16, 33, false, xth, xtl, h1h[(t+1)&1], h1l[(t+1)&1], ndA, Wh0, Wl0);
    if (t >= 2) flag_wait((t-2)*8 + 4 + mt);          // WAR: L1(t-2) done reading h1 buffer t&1
    epilogue(bias0, c1r, h1h[t&1], h1l[t&1], term_t);
    flag_post(t*8 + mt);

    // ===== layer 1: gates = [h1(t) | h2(t-1)*nd] @ W1^T ; h2(t-1) = x[t-1] alias =====
    zacc();
    if (t >= 1){
      flag_wait((t-1)*8 + 4 + mt);                    // x[t-1] (= h2(t-1)) ready
      runrange(17, 33, true, h1h[t&1], h1l[t&1], xph, xpl, ndA, Wh1, Wl1);  // pure h2 slabs
    }
    flag_wait(t*8 + mt);                              // h1(t) ready (all strips)
    runrange(0, 17, true, h1h[t&1], h1l[t&1], xph, xpl, ndA, Wh1, Wl1);
    epilogue(bias1, c2r, xth, xtl, term_t);           // h2(t) overwrites x[t] (bypass stores)
    flag_post(t*8 + 4 + mt);
  }
}

// ---------------- heads: logits/baseline/action ----------------
__launch_bounds__(256)
__global__ void k_heads(const _Float16* __restrict__ oh, const _Float16* __restrict__ ol,
                        const float* __restrict__ polw, const float* __restrict__ basew,
                        const float* __restrict__ polb, const float* __restrict__ baseb,
                        float* __restrict__ dout){
  __shared__ _Float16 Ah[128][40], Al[128][40];
  __shared__ _Float16 Bh[16][552], Bl[16][552];
  const int bid = blockIdx.x;
  const int tid = threadIdx.x, w = tid >> 6, l = tid & 63;
  const int m0 = bid*128;

  for (int i = tid; i < 16*544; i += 256){
    int r = i / 544, c = i % 544;
    float v = 0.f;
    if (c < DD) v = (r < NA) ? polw[r*DD + c] : basew[c];
    split1(v, Bh[r][c], Bl[r][c]);
  }
  __syncthreads();

  f32x4 acc1[2], acc2[2];
  #pragma unroll
  for (int m = 0; m < 2; ++m)
    #pragma unroll
    for (int q = 0; q < 4; ++q){ acc1[m][q]=0.f; acc2[m][q]=0.f; }

  for (int it = 0; it < 17; ++it){
    const int k0 = it*32;
    {
      int row = tid >> 1, c0 = (tid & 1)*16;
      size_t off = (size_t)(m0+row)*DD + k0 + c0;   // overreads pad; B=0 there
      *(half8*)&Ah[row][c0]   = *(const half8*)(oh + off);
      *(half8*)&Ah[row][c0+8] = *(const half8*)(oh + off + 8);
      *(half8*)&Al[row][c0]   = *(const half8*)(ol + off);
      *(half8*)&Al[row][c0+8] = *(const half8*)(ol + off + 8);
    }
    __syncthreads();
    half8 fbh = *(const half8*)&Bh[l & 15][k0 + (l >> 4)*8];
    half8 fbl = *(const half8*)&Bl[l & 15][k0 + (l >> 4)*8];
    #pragma unroll
    for (int m = 0; m < 2; ++m){
      half8 fah = *(const half8*)&Ah[w*32 + m*16 + (l & 15)][(l >> 4)*8];
      half8 fal = *(const half8*)&Al[w*32 + m*16 + (l & 15)][(l >> 4)*8];
      acc1[m] = __builtin_amdgcn_mfma_f32_16x16x32_f16(fah, fbh, acc1[m], 0, 0, 0);
      acc2[m] = __builtin_amdgcn_mfma_f32_16x16x32_f16(fah, fbl, acc2[m], 0, 0, 0);
      acc2[m] = __builtin_amdgcn_mfma_f32_16x16x32_f16(fal, fbh, acc2[m], 0, 0, 0);
    }
    __syncthreads();
  }

  const int a = l & 15;
  const size_t base_off = (size_t)TT*BB*NA;
  const size_t act_off  = base_off + (size_t)TT*BB;
  #pragma unroll
  for (int m = 0; m < 2; ++m)
    #pragma unroll
    for (int q = 0; q < 4; ++q){
      int r = m0 + w*32 + m*16 + (l >> 4)*4 + q;
      float v = acc1[m][q] + acc2[m][q]*INV_SCL + ((a < NA) ? polb[a] : baseb[0]);
      float key = (a < NA) ? v : -3.4e38f;
      int ki = a;
      #pragma unroll
      for (int s = 1; s < 16; s <<= 1){
        float ov = __shfl_xor(key, s, 64);
        int   oi = __shfl_xor(ki,  s, 64);
        if (ov > key || (ov == key && oi < ki)){ key = ov; ki = oi; }
      }
      if (a < NA) dout[(size_t)r*NA + a] = v;
      if (a == NA) dout[base_off + r] = v;
      if (a == 0)  dout[act_off + r] = (float)ki;
    }
}

// ---------------- launch ----------------
extern "C" void kernel_launch(void* const* d_in, const int* in_sizes, int n_in,
                              void* d_out, int out_size, void* d_ws, size_t ws_size,
                              hipStream_t stream){
  const float* obs        = (const float*)d_in[0];
  const int*   last_act   = (const int*)  d_in[1];
  const float* reward     = (const float*)d_in[2];
  const int*   terminated = (const int*)  d_in[3];
  const float* enc_w      = (const float*)d_in[4];
  const float* enc_b      = (const float*)d_in[5];
  const float* w_ih0      = (const float*)d_in[6];
  const float* w_hh0      = (const float*)d_in[7];
  const float* b_ih0      = (const float*)d_in[8];
  const float* b_hh0      = (const float*)d_in[9];
  const float* w_ih1      = (const float*)d_in[10];
  const float* w_hh1      = (const float*)d_in[11];
  const float* b_ih1      = (const float*)d_in[12];
  const float* b_hh1      = (const float*)d_in[13];
  const float* pol_w      = (const float*)d_in[14];
  const float* pol_b      = (const float*)d_in[15];
  const float* base_w     = (const float*)d_in[16];
  const float* base_b     = (const float*)d_in[17];

  char* ws = (char*)d_ws;
  size_t o = 0;
  auto alloc = [&](size_t bytes){ size_t r = o; o += (bytes + 255) & ~(size_t)255; return r; };

  _Float16* Wh0   = (_Float16*)(ws + alloc((size_t)GG*KK*2));
  _Float16* Wl0   = (_Float16*)(ws + alloc((size_t)GG*KK*2));
  _Float16* Wh1   = (_Float16*)(ws + alloc((size_t)GG*KK*2));
  _Float16* Wl1   = (_Float16*)(ws + alloc((size_t)GG*KK*2));
  float* bias0    = (float*)(ws + alloc((size_t)GG*4));
  float* bias1    = (float*)(ws + alloc((size_t)GG*4));
  _Float16* ench  = (_Float16*)(ws + alloc((size_t)FEATD*OBSD*2));
  _Float16* encl  = (_Float16*)(ws + alloc((size_t)FEATD*OBSD*2));
  _Float16* xh    = (_Float16*)(ws + alloc((size_t)TT*BB*DD*2 + 4096));  // x / h2-out hi plane
  _Float16* xl    = (_Float16*)(ws + alloc((size_t)TT*BB*DD*2 + 4096));  // lo plane
  _Float16* h1h0  = (_Float16*)(ws + alloc((size_t)BB*DD*2));
  _Float16* h1l0  = (_Float16*)(ws + alloc((size_t)BB*DD*2));
  _Float16* h1h1  = (_Float16*)(ws + alloc((size_t)BB*DD*2));
  _Float16* h1l1  = (_Float16*)(ws + alloc((size_t)BB*DD*2));
  int*   flags    = (int*)(ws + alloc((size_t)TT*8*4));

  hipMemsetAsync(flags, 0, (size_t)TT*8*4, stream);

  k_prep_w<<<2048, 256, 0, stream>>>(w_ih0, w_hh0, b_ih0, b_hh0, Wh0, Wl0, bias0);
  k_prep_w<<<2048, 256, 0, stream>>>(w_ih1, w_hh1, b_ih1, b_hh1, Wh1, Wl1, bias1);
  k_conv_encw<<<2048, 256, 0, stream>>>(enc_w, ench, encl);
  k_fill_extra<<<TT*BB/256, 256, 0, stream>>>(reward, last_act, xh, xl);

  dim3 eg(TT*BB/128, FEATD/128);
  k_encoder<<<eg, 256, 0, stream>>>(obs, ench, encl, enc_b, xh, xl);

  k_recur<<<132, 256, 0, stream>>>(xh, xl, h1h0, h1l0, h1h1, h1l1,
                                   Wh0, Wl0, Wh1, Wl1, bias0, bias1,
                                   terminated, flags);

  k_heads<<<TT*BB/128, 256, 0, stream>>>(xh, xl, pol_w, base_w, pol_b, base_b, (float*)d_out);
}

// Round 5
// 4641.945 us; speedup vs baseline: 8.5928x; 1.2735x over previous
//
#include <hip/hip_runtime.h>
#include <hip/hip_bf16.h>

#define TT 128
#define BB 256
#define OBSD 1024
#define FEATD 512
#define NA 15
#define DD 528
#define GG 2112   // 4*DD
#define KK 1056   // 2*DD
#define SCL 4096.f
#define INV_SCL (1.f/4096.f)

using half8 = __attribute__((ext_vector_type(8))) _Float16;
using f32x4 = __attribute__((ext_vector_type(4))) float;

__device__ __forceinline__ void split1(float v, _Float16& h, _Float16& l){
  h = (_Float16)v;
  l = (_Float16)((v - (float)h) * SCL);
}
__device__ __forceinline__ float sigf(float x){ return 1.f/(1.f + expf(-x)); }

// global->LDS direct staging. aux=17 = SC0|SC1 (device-coherent, executes at L3,
// bypasses possibly-stale per-XCD L2). aux=0 = normal cached.
#define GLOAD_LDS(g, s, aux) \
  __builtin_amdgcn_global_load_lds((const __attribute__((address_space(1))) void*)(g), \
                                   (__attribute__((address_space(3))) void*)(s), 16, 0, (aux))

// ---------------- prep kernels ----------------

__global__ void k_prep_w(const float* __restrict__ wih, const float* __restrict__ whh,
                         const float* __restrict__ bih, const float* __restrict__ bhh,
                         _Float16* __restrict__ Wh, _Float16* __restrict__ Wl,
                         float* __restrict__ bias){
  const int n = GG*KK;
  for (int i = blockIdx.x*blockDim.x + threadIdx.x; i < n; i += gridDim.x*blockDim.x){
    int r = i / KK, c = i % KK;
    float v = (c < DD) ? wih[r*DD + c] : whh[r*DD + (c - DD)];
    split1(v, Wh[i], Wl[i]);
    if (i < GG) bias[i] = bih[i] + bhh[i];
  }
}

__global__ void k_conv_encw(const float* __restrict__ src,
                            _Float16* __restrict__ dh, _Float16* __restrict__ dl){
  const int n = FEATD*OBSD;
  for (int i = blockIdx.x*blockDim.x + threadIdx.x; i < n; i += gridDim.x*blockDim.x)
    split1(src[i], dh[i], dl[i]);
}

__global__ void k_fill_extra(const float* __restrict__ reward, const int* __restrict__ act,
                             _Float16* __restrict__ xh, _Float16* __restrict__ xl){
  int row = blockIdx.x*blockDim.x + threadIdx.x;
  if (row >= TT*BB) return;
  float r = fminf(1.f, fmaxf(-1.f, reward[row]));
  size_t base = (size_t)row*DD + FEATD;
  _Float16 hh, hl;
  split1(r, hh, hl);
  xh[base] = hh; xl[base] = hl;
  int a = act[row];
  #pragma unroll
  for (int i = 0; i < NA; ++i){
    xh[base+1+i] = (i == a) ? (_Float16)1.0f : (_Float16)0.0f;
    xl[base+1+i] = (_Float16)0.0f;
  }
}

// ---------------- encoder GEMM -> x planes cols 0..511 ----------------
__launch_bounds__(256)
__global__ void k_encoder(const float* __restrict__ obs, const _Float16* __restrict__ ench,
                          const _Float16* __restrict__ encl,
                          const float* __restrict__ encb,
                          _Float16* __restrict__ xh, _Float16* __restrict__ xl){
  __shared__ _Float16 Ah[128][40], Al[128][40], Bh[128][40], Bl[128][40];
  const int mt = blockIdx.x, nt = blockIdx.y;
  const int tid = threadIdx.x, w = tid >> 6, l = tid & 63;
  const int wm = (w >> 1)*64, wn = (w & 1)*64;
  const int m0 = mt*128, n0 = nt*128;
  f32x4 acc1[4][4], acc2[4][4];
  #pragma unroll
  for (int m = 0; m < 4; ++m)
    #pragma unroll
    for (int n = 0; n < 4; ++n)
      #pragma unroll
      for (int q = 0; q < 4; ++q){ acc1[m][n][q]=0.f; acc2[m][n][q]=0.f; }

  for (int k0 = 0; k0 < OBSD; k0 += 32){
    {
      int row = tid >> 1, c0 = (tid & 1)*16;
      const float* src = obs + (size_t)(m0+row)*OBSD + k0 + c0;
      #pragma unroll
      for (int cc = 0; cc < 16; ++cc){
        float v = src[cc];
        split1(v, Ah[row][c0+cc], Al[row][c0+cc]);
      }
      const _Float16* bh = ench + (size_t)(n0+row)*OBSD + k0 + c0;
      const _Float16* bl = encl + (size_t)(n0+row)*OBSD + k0 + c0;
      *(half8*)&Bh[row][c0]   = *(const half8*)(bh);
      *(half8*)&Bh[row][c0+8] = *(const half8*)(bh+8);
      *(half8*)&Bl[row][c0]   = *(const half8*)(bl);
      *(half8*)&Bl[row][c0+8] = *(const half8*)(bl+8);
    }
    __syncthreads();
    half8 ah[4], al[4], bh[4], bl[4];
    #pragma unroll
    for (int m = 0; m < 4; ++m){
      ah[m] = *(const half8*)&Ah[wm + m*16 + (l & 15)][(l >> 4)*8];
      al[m] = *(const half8*)&Al[wm + m*16 + (l & 15)][(l >> 4)*8];
    }
    #pragma unroll
    for (int n = 0; n < 4; ++n){
      bh[n] = *(const half8*)&Bh[wn + n*16 + (l & 15)][(l >> 4)*8];
      bl[n] = *(const half8*)&Bl[wn + n*16 + (l & 15)][(l >> 4)*8];
    }
    #pragma unroll
    for (int m = 0; m < 4; ++m)
      #pragma unroll
      for (int n = 0; n < 4; ++n){
        acc1[m][n] = __builtin_amdgcn_mfma_f32_16x16x32_f16(ah[m], bh[n], acc1[m][n], 0, 0, 0);
        acc2[m][n] = __builtin_amdgcn_mfma_f32_16x16x32_f16(ah[m], bl[n], acc2[m][n], 0, 0, 0);
        acc2[m][n] = __builtin_amdgcn_mfma_f32_16x16x32_f16(al[m], bh[n], acc2[m][n], 0, 0, 0);
      }
    __syncthreads();
  }
  #pragma unroll
  for (int m = 0; m < 4; ++m)
    #pragma unroll
    for (int n = 0; n < 4; ++n)
      #pragma unroll
      for (int q = 0; q < 4; ++q){
        int row = m0 + wm + m*16 + (l >> 4)*4 + q;
        int col = n0 + wn + n*16 + (l & 15);
        float v = acc1[m][n][q] + acc2[m][n][q]*INV_SCL + encb[col];
        v = fmaxf(v, 0.f);
        _Float16 hh, hl;
        split1(v, hh, hl);
        size_t off = (size_t)row*DD + col;
        xh[off] = hh; xl[off] = hl;
      }
}

// ---------------- persistent recurrence kernel ----------------
// 132 blocks: mt = bid&3 (64-row batch tile), js = bid>>2 (16-wide hidden strip).
// Staging: global_load_lds direct (aux=17 for h planes -> L3-coherent coalesced;
// aux=0 for W). 4 LDS slots, depth-3 prefetch, counted vmcnt, raw barriers.
// Wave w computes rows 16w..16w+15 x all 4 gates; c-state in registers.
__launch_bounds__(256)
__global__ void k_recur(_Float16* xh, _Float16* xl,
                        _Float16* h1h0, _Float16* h1l0,
                        _Float16* h1h1, _Float16* h1l1,
                        const _Float16* __restrict__ Wh0, const _Float16* __restrict__ Wl0,
                        const _Float16* __restrict__ Wh1, const _Float16* __restrict__ Wl1,
                        const float* __restrict__ bias0, const float* __restrict__ bias1,
                        const int* __restrict__ term, int* flags,
                        const _Float16* __restrict__ zp){
  // S[slot][plane][row][col] : plane 0=Ah 1=Al 2=Bh 3=Bl ; [64][32] f16, linear
  __shared__ _Float16 S[4][4][64][32];

  const int tid = threadIdx.x, w = tid >> 6, l = tid & 63;
  const int bid = blockIdx.x, mt = bid & 3, js = bid >> 2;
  const int m0 = mt*64, j0 = js*16;
  const int aRow = m0 + w*16 + (l >> 2);       // staging A row (this lane)
  const int acol = (l & 3)*8;                  // staging col offset within slab
  const int wRowH = w*DD + j0 + (l >> 2);      // W row staged by this lane (gate=w)
  const int prow0 = m0 + w*16 + ((l >> 4) << 2);
  const int jcol = j0 + (l & 15);

  float c1r[4] = {0.f,0.f,0.f,0.f};
  float c2r[4] = {0.f,0.f,0.f,0.f};
  f32x4 accm[4], accc[4];

  auto flag_wait = [&](int idx){
    if (tid == 0){
      while (__hip_atomic_load(&flags[idx], __ATOMIC_RELAXED, __HIP_MEMORY_SCOPE_AGENT) < 33)
        __builtin_amdgcn_s_sleep(2);
    }
    __builtin_amdgcn_s_barrier();
    __builtin_amdgcn_sched_barrier(0);
  };
  auto flag_post = [&](int idx){
    asm volatile("s_waitcnt vmcnt(0)" ::: "memory");   // own stores at L3
    __builtin_amdgcn_s_barrier();                      // all threads drained
    if (tid == 0)
      __hip_atomic_fetch_add(&flags[idx], 1, __ATOMIC_RELAXED, __HIP_MEMORY_SCOPE_AGENT);
  };

  auto run_phase = [&](bool isL1, int t,
                       const _Float16* p1h, const _Float16* p1l,
                       const _Float16* p2h, const _Float16* p2l, bool ndA,
                       const _Float16* Wh, const _Float16* Wl,
                       int wA_i, int wA_f, int wB_i, int wB_f){
    #pragma unroll
    for (int g = 0; g < 4; ++g)
      #pragma unroll
      for (int q = 0; q < 4; ++q){ accm[g][q] = 0.f; accc[g][q] = 0.f; }

    auto issue = [&](int i){
      if (i == wA_i && wA_f >= 0) flag_wait(wA_f);
      if (i == wB_i && wB_f >= 0) flag_wait(wB_f);
      const int s = isL1 ? (i < 16 ? 17 + i : i - 16) : i;   // slab order permutation
      const int slot = i & 3;
      const int col = s*32 + acol;
      const _Float16 *gph, *gpl;
      if (col < DD){
        size_t off = (size_t)aRow*DD + col;
        gph = p1h + off; gpl = p1l + off;
      } else if (ndA){
        size_t off = (size_t)aRow*DD + (col - DD);
        gph = p2h + off; gpl = p2l + off;
      } else {
        gph = zp; gpl = zp;
      }
      _Float16* dAh = &S[slot][0][w*16][0];
      _Float16* dAl = &S[slot][1][w*16][0];
      _Float16* dBh = &S[slot][2][w*16][0];
      _Float16* dBl = &S[slot][3][w*16][0];
      const _Float16* gbh = Wh + (size_t)wRowH*KK + col;
      const _Float16* gbl = Wl + (size_t)wRowH*KK + col;
      if (isL1 || s >= 16){   // h-plane data: L3-coherent
        GLOAD_LDS(gph, dAh, 17);
        GLOAD_LDS(gpl, dAl, 17);
      } else {                // pure-x slab: cached
        GLOAD_LDS(gph, dAh, 0);
        GLOAD_LDS(gpl, dAl, 0);
      }
      GLOAD_LDS(gbh, dBh, 0);
      GLOAD_LDS(gbl, dBl, 0);
    };

    issue(0); issue(1); issue(2);
    #pragma unroll 1
    for (int i = 0; i < 33; ++i){
      if (i < 31)       asm volatile("s_waitcnt vmcnt(8)" ::: "memory");
      else if (i == 31) asm volatile("s_waitcnt vmcnt(4)" ::: "memory");
      else              asm volatile("s_waitcnt vmcnt(0)" ::: "memory");
      __builtin_amdgcn_s_barrier();
      __builtin_amdgcn_sched_barrier(0);
      if (i + 3 < 33) issue(i + 3);
      const int slot = i & 3;
      half8 fah = *(const half8*)&S[slot][0][w*16 + (l & 15)][(l >> 4)*8];
      half8 fal = *(const half8*)&S[slot][1][w*16 + (l & 15)][(l >> 4)*8];
      #pragma unroll
      for (int g = 0; g < 4; ++g){
        half8 fbh = *(const half8*)&S[slot][2][g*16 + (l & 15)][(l >> 4)*8];
        half8 fbl = *(const half8*)&S[slot][3][g*16 + (l & 15)][(l >> 4)*8];
        accm[g] = __builtin_amdgcn_mfma_f32_16x16x32_f16(fah, fbh, accm[g], 0, 0, 0);
        accc[g] = __builtin_amdgcn_mfma_f32_16x16x32_f16(fah, fbl, accc[g], 0, 0, 0);
        accc[g] = __builtin_amdgcn_mfma_f32_16x16x32_f16(fal, fbh, accc[g], 0, 0, 0);
      }
    }
  };

  auto epilogue = [&](const float* bias, float* cr, _Float16* dh, _Float16* dl,
                      const int* term_t){
    #pragma unroll
    for (int q = 0; q < 4; ++q){
      const int row = prow0 + q;
      float iv = accm[0][q] + accc[0][q]*INV_SCL + bias[jcol];
      float fv = accm[1][q] + accc[1][q]*INV_SCL + bias[DD + jcol];
      float gv = accm[2][q] + accc[2][q]*INV_SCL + bias[2*DD + jcol];
      float ov = accm[3][q] + accc[3][q]*INV_SCL + bias[3*DD + jcol];
      float cp = (term_t[row] == 0) ? cr[q] : 0.f;
      float cn = sigf(fv)*cp + sigf(iv)*tanhf(gv);
      float hn = sigf(ov)*tanhf(cn);
      cr[q] = cn;
      _Float16 hh, hl;
      split1(hn, hh, hl);
      size_t off = (size_t)row*DD + jcol;
      __hip_atomic_store((unsigned short*)(dh + off), __builtin_bit_cast(unsigned short, hh),
                         __ATOMIC_RELAXED, __HIP_MEMORY_SCOPE_AGENT);
      __hip_atomic_store((unsigned short*)(dl + off), __builtin_bit_cast(unsigned short, hl),
                         __ATOMIC_RELAXED, __HIP_MEMORY_SCOPE_AGENT);
    }
  };

  _Float16* h1h[2] = {h1h0, h1h1};
  _Float16* h1l[2] = {h1l0, h1l1};

  #pragma unroll 1
  for (int t = 0; t < TT; ++t){
    const int* term_t = term + t*BB;
    const bool ndA = (t > 0) && (term_t[aRow] == 0);
    _Float16* xth = xh + (size_t)t*BB*DD;
    _Float16* xtl = xl + (size_t)t*BB*DD;
    const _Float16* xph = xh + (size_t)(t > 0 ? t-1 : 0)*BB*DD;
    const _Float16* xpl = xl + (size_t)(t > 0 ? t-1 : 0)*BB*DD;

    // ===== layer 0: gates = [x(t) | h1(t-1)*nd] @ W0^T =====
    run_phase(false, t, xth, xtl, h1h[(t+1)&1], h1l[(t+1)&1], ndA, Wh0, Wl0,
              16, (t >= 1) ? (t-1)*8 + mt : -1, -1, -1);
    if (t >= 2) flag_wait((t-2)*8 + 4 + mt);           // WAR on h1 buffer t&1
    epilogue(bias0, c1r, h1h[t&1], h1l[t&1], term_t);
    flag_post(t*8 + mt);

    // ===== layer 1: gates = [h1(t) | h2(t-1)*nd] @ W1^T ; h2(t-1)=x[t-1] alias =====
    run_phase(true, t, h1h[t&1], h1l[t&1], xph, xpl, ndA, Wh1, Wl1,
              0, (t >= 1) ? (t-1)*8 + 4 + mt : -1,
              16, t*8 + mt);
    epilogue(bias1, c2r, xth, xtl, term_t);            // h2(t) overwrites x[t]
    flag_post(t*8 + 4 + mt);
  }
}

// ---------------- heads: logits/baseline/action ----------------
__launch_bounds__(256)
__global__ void k_heads(const _Float16* __restrict__ oh, const _Float16* __restrict__ ol,
                        const float* __restrict__ polw, const float* __restrict__ basew,
                        const float* __restrict__ polb, const float* __restrict__ baseb,
                        float* __restrict__ dout){
  __shared__ _Float16 Ah[128][40], Al[128][40];
  __shared__ _Float16 Bh[16][552], Bl[16][552];
  const int bid = blockIdx.x;
  const int tid = threadIdx.x, w = tid >> 6, l = tid & 63;
  const int m0 = bid*128;

  for (int i = tid; i < 16*544; i += 256){
    int r = i / 544, c = i % 544;
    float v = 0.f;
    if (c < DD) v = (r < NA) ? polw[r*DD + c] : basew[c];
    split1(v, Bh[r][c], Bl[r][c]);
  }
  __syncthreads();

  f32x4 acc1[2], acc2[2];
  #pragma unroll
  for (int m = 0; m < 2; ++m)
    #pragma unroll
    for (int q = 0; q < 4; ++q){ acc1[m][q]=0.f; acc2[m][q]=0.f; }

  for (int it = 0; it < 17; ++it){
    const int k0 = it*32;
    {
      int row = tid >> 1, c0 = (tid & 1)*16;
      size_t off = (size_t)(m0+row)*DD + k0 + c0;   // overreads pad; B=0 there
      *(half8*)&Ah[row][c0]   = *(const half8*)(oh + off);
      *(half8*)&Ah[row][c0+8] = *(const half8*)(oh + off + 8);
      *(half8*)&Al[row][c0]   = *(const half8*)(ol + off);
      *(half8*)&Al[row][c0+8] = *(const half8*)(ol + off + 8);
    }
    __syncthreads();
    half8 fbh = *(const half8*)&Bh[l & 15][k0 + (l >> 4)*8];
    half8 fbl = *(const half8*)&Bl[l & 15][k0 + (l >> 4)*8];
    #pragma unroll
    for (int m = 0; m < 2; ++m){
      half8 fah = *(const half8*)&Ah[w*32 + m*16 + (l & 15)][(l >> 4)*8];
      half8 fal = *(const half8*)&Al[w*32 + m*16 + (l & 15)][(l >> 4)*8];
      acc1[m] = __builtin_amdgcn_mfma_f32_16x16x32_f16(fah, fbh, acc1[m], 0, 0, 0);
      acc2[m] = __builtin_amdgcn_mfma_f32_16x16x32_f16(fah, fbl, acc2[m], 0, 0, 0);
      acc2[m] = __builtin_amdgcn_mfma_f32_16x16x32_f16(fal, fbh, acc2[m], 0, 0, 0);
    }
    __syncthreads();
  }

  const int a = l & 15;
  const size_t base_off = (size_t)TT*BB*NA;
  const size_t act_off  = base_off + (size_t)TT*BB;
  #pragma unroll
  for (int m = 0; m < 2; ++m)
    #pragma unroll
    for (int q = 0; q < 4; ++q){
      int r = m0 + w*32 + m*16 + (l >> 4)*4 + q;
      float v = acc1[m][q] + acc2[m][q]*INV_SCL + ((a < NA) ? polb[a] : baseb[0]);
      float key = (a < NA) ? v : -3.4e38f;
      int ki = a;
      #pragma unroll
      for (int s = 1; s < 16; s <<= 1){
        float ov = __shfl_xor(key, s, 64);
        int   oi = __shfl_xor(ki,  s, 64);
        if (ov > key || (ov == key && oi < ki)){ key = ov; ki = oi; }
      }
      if (a < NA) dout[(size_t)r*NA + a] = v;
      if (a == NA) dout[base_off + r] = v;
      if (a == 0)  dout[act_off + r] = (float)ki;
    }
}

// ---------------- launch ----------------
extern "C" void kernel_launch(void* const* d_in, const int* in_sizes, int n_in,
                              void* d_out, int out_size, void* d_ws, size_t ws_size,
                              hipStream_t stream){
  const float* obs        = (const float*)d_in[0];
  const int*   last_act   = (const int*)  d_in[1];
  const float* reward     = (const float*)d_in[2];
  const int*   terminated = (const int*)  d_in[3];
  const float* enc_w      = (const float*)d_in[4];
  const float* enc_b      = (const float*)d_in[5];
  const float* w_ih0      = (const float*)d_in[6];
  const float* w_hh0      = (const float*)d_in[7];
  const float* b_ih0      = (const float*)d_in[8];
  const float* b_hh0      = (const float*)d_in[9];
  const float* w_ih1      = (const float*)d_in[10];
  const float* w_hh1      = (const float*)d_in[11];
  const float* b_ih1      = (const float*)d_in[12];
  const float* b_hh1      = (const float*)d_in[13];
  const float* pol_w      = (const float*)d_in[14];
  const float* pol_b      = (const float*)d_in[15];
  const float* base_w     = (const float*)d_in[16];
  const float* base_b     = (const float*)d_in[17];

  char* ws = (char*)d_ws;
  size_t o = 0;
  auto alloc = [&](size_t bytes){ size_t r = o; o += (bytes + 255) & ~(size_t)255; return r; };

  _Float16* Wh0   = (_Float16*)(ws + alloc((size_t)GG*KK*2));
  _Float16* Wl0   = (_Float16*)(ws + alloc((size_t)GG*KK*2));
  _Float16* Wh1   = (_Float16*)(ws + alloc((size_t)GG*KK*2));
  _Float16* Wl1   = (_Float16*)(ws + alloc((size_t)GG*KK*2));
  float* bias0    = (float*)(ws + alloc((size_t)GG*4));
  float* bias1    = (float*)(ws + alloc((size_t)GG*4));
  _Float16* ench  = (_Float16*)(ws + alloc((size_t)FEATD*OBSD*2));
  _Float16* encl  = (_Float16*)(ws + alloc((size_t)FEATD*OBSD*2));
  _Float16* xh    = (_Float16*)(ws + alloc((size_t)TT*BB*DD*2 + 4096));  // x / h2-out hi
  _Float16* xl    = (_Float16*)(ws + alloc((size_t)TT*BB*DD*2 + 4096));  // lo plane
  _Float16* h1h0  = (_Float16*)(ws + alloc((size_t)BB*DD*2));
  _Float16* h1l0  = (_Float16*)(ws + alloc((size_t)BB*DD*2));
  _Float16* h1h1  = (_Float16*)(ws + alloc((size_t)BB*DD*2));
  _Float16* h1l1  = (_Float16*)(ws + alloc((size_t)BB*DD*2));
  int*   flags    = (int*)(ws + alloc((size_t)TT*8*4 + 256));   // + zero page
  _Float16* zp    = (_Float16*)((char*)flags + TT*8*4);

  hipMemsetAsync(flags, 0, (size_t)TT*8*4 + 256, stream);

  k_prep_w<<<2048, 256, 0, stream>>>(w_ih0, w_hh0, b_ih0, b_hh0, Wh0, Wl0, bias0);
  k_prep_w<<<2048, 256, 0, stream>>>(w_ih1, w_hh1, b_ih1, b_hh1, Wh1, Wl1, bias1);
  k_conv_encw<<<2048, 256, 0, stream>>>(enc_w, ench, encl);
  k_fill_extra<<<TT*BB/256, 256, 0, stream>>>(reward, last_act, xh, xl);

  dim3 eg(TT*BB/128, FEATD/128);
  k_encoder<<<eg, 256, 0, stream>>>(obs, ench, encl, enc_b, xh, xl);

  k_recur<<<132, 256, 0, stream>>>(xh, xl, h1h0, h1l0, h1h1, h1l1,
                                   Wh0, Wl0, Wh1, Wl1, bias0, bias1,
                                   terminated, flags, zp);

  k_heads<<<TT*BB/128, 256, 0, stream>>>(xh, xl, pol_w, base_w, pol_b, base_b, (float*)d_out);
}